// Round 9
// baseline (7322.524 us; speedup 1.0000x reference)
//
#include <hip/hip_runtime.h>

#define T_LEN 4096
#define EMB   300
#define HD    256
#define G4    1024      // 4*HD (gate rows per direction)
#define N2    2048      // both directions
#define TAGS  12
#define NEGV  -10000.0f
#define SENT  0x7F7F7F7Fu   // memset byte 0x7F -> 3.39e38f; |h|<1 so never produced

// ---------------------------------------------------------------------------
// Kernel 1: g_in[t][dir*1024 + r] = embed[sent[t]] . W_ih_dir[r] + b_ih + b_hh
// 64x64 tiles, 256 thr, 4x4 acc, transposed LDS staging.
// ---------------------------------------------------------------------------
__global__ __launch_bounds__(256) void gin_gemm(
    const int* __restrict__ sent, const float* __restrict__ embed,
    const float* __restrict__ Wf, const float* __restrict__ Wb,
    const float* __restrict__ bihf, const float* __restrict__ bhhf,
    const float* __restrict__ bihb, const float* __restrict__ bhhb,
    float* __restrict__ gin)
{
    __shared__ float AsT[32][68];
    __shared__ float BsT[32][68];
    __shared__ int   sIdx[64];
    const int tid = threadIdx.x;
    const int bn = blockIdx.x;   // 0..31  (N tiles over 2048)
    const int bm = blockIdx.y;   // 0..63  (M tiles over 4096)
    if (tid < 64) sIdx[tid] = sent[bm*64 + tid];
    __syncthreads();

    float acc[4][4] = {};
    const int lr = tid >> 3;          // 0..31
    const int lk = (tid & 7) << 2;    // 0,4,..,28
    const int m0 = (tid >> 4) << 2;
    const int n0 = (tid & 15) << 2;

    for (int kc = 0; kc < 10; ++kc) {           // K chunks of 32 (covers 320, guard 300)
        const int k0 = kc*32 + lk;
        #pragma unroll
        for (int h = 0; h < 2; ++h) {
            const int row = lr + h*32;
            float4 va = make_float4(0.f,0.f,0.f,0.f);
            if (k0 + 3 < EMB)   // EMB % 4 == 0: vectors are all-or-nothing
                va = *(const float4*)(embed + (long)sIdx[row]*EMB + k0);
            AsT[lk+0][row]=va.x; AsT[lk+1][row]=va.y;
            AsT[lk+2][row]=va.z; AsT[lk+3][row]=va.w;

            const int rn = bn*64 + row;          // tiles never straddle the 1024 split
            const float* bsrc = (rn < G4) ? (Wf + (long)rn*EMB) : (Wb + (long)(rn-G4)*EMB);
            float4 vb = make_float4(0.f,0.f,0.f,0.f);
            if (k0 + 3 < EMB)
                vb = *(const float4*)(bsrc + k0);
            BsT[lk+0][row]=vb.x; BsT[lk+1][row]=vb.y;
            BsT[lk+2][row]=vb.z; BsT[lk+3][row]=vb.w;
        }
        __syncthreads();
        #pragma unroll
        for (int kk = 0; kk < 32; ++kk) {
            const float4 a4 = *(const float4*)&AsT[kk][m0];
            const float4 b4 = *(const float4*)&BsT[kk][n0];
            const float a[4] = {a4.x, a4.y, a4.z, a4.w};
            const float b[4] = {b4.x, b4.y, b4.z, b4.w};
            #pragma unroll
            for (int i = 0; i < 4; ++i)
                #pragma unroll
                for (int jj = 0; jj < 4; ++jj)
                    acc[i][jj] = fmaf(a[i], b[jj], acc[i][jj]);
        }
        __syncthreads();
    }

    #pragma unroll
    for (int i = 0; i < 4; ++i) {
        const int t = bm*64 + m0 + i;
        #pragma unroll
        for (int jj = 0; jj < 4; ++jj) {
            const int r = bn*64 + n0 + jj;
            const float bias = (r < G4) ? (bihf[r] + bhhf[r])
                                        : (bihb[r-G4] + bhhb[r-G4]);
            gin[(long)t*N2 + r] = acc[i][jj] + bias;
        }
    }
}

// ---------------------------------------------------------------------------
// Kernel 2: persistent BiLSTM, 4 blocks x 1024 thr per direction.
// r8 structure (quarter gate-rows, 64 weights/thread, one-hop sentinel
// exchange) with the h-broadcast redesigned:
//  * h window loaded LANE-SPREAD: lane l holds h[win+(l&3)*16 .. +15]
//    (4 x ds_read_b128/wave instead of 16 uniform reads).
//  * FMA uses DPP quad_perm:[q,q,q,q] to broadcast quad-lane q's h value
//    to all lanes at use time — one VOP2 v_fmac per MAC, no LDS traffic.
//  * hS declared 80 KB -> LDS-forced 1 block/CU, so the register allocator
//    has no occupancy reason to spill below the 128-VGPR/wave cap.
// ---------------------------------------------------------------------------
#define FMA8(Q, RR0)                                                          \
    asm volatile(                                                             \
        "s_nop 1\n\t"                                                         \
        "v_fmac_f32 %0, %4,  %12 quad_perm:[" #Q "," #Q "," #Q "," #Q "] row_mask:0xf bank_mask:0xf\n\t" \
        "v_fmac_f32 %1, %5,  %13 quad_perm:[" #Q "," #Q "," #Q "," #Q "] row_mask:0xf bank_mask:0xf\n\t" \
        "v_fmac_f32 %2, %6,  %14 quad_perm:[" #Q "," #Q "," #Q "," #Q "] row_mask:0xf bank_mask:0xf\n\t" \
        "v_fmac_f32 %3, %7,  %15 quad_perm:[" #Q "," #Q "," #Q "," #Q "] row_mask:0xf bank_mask:0xf\n\t" \
        "v_fmac_f32 %0, %8,  %16 quad_perm:[" #Q "," #Q "," #Q "," #Q "] row_mask:0xf bank_mask:0xf\n\t" \
        "v_fmac_f32 %1, %9,  %17 quad_perm:[" #Q "," #Q "," #Q "," #Q "] row_mask:0xf bank_mask:0xf\n\t" \
        "v_fmac_f32 %2, %10, %18 quad_perm:[" #Q "," #Q "," #Q "," #Q "] row_mask:0xf bank_mask:0xf\n\t" \
        "v_fmac_f32 %3, %11, %19 quad_perm:[" #Q "," #Q "," #Q "," #Q "] row_mask:0xf bank_mask:0xf\n\t" \
        : "+v"(ac0), "+v"(ac1), "+v"(ac2), "+v"(ac3)                          \
        : "v"(hr[RR0+0]), "v"(hr[RR0+1]), "v"(hr[RR0+2]), "v"(hr[RR0+3]),     \
          "v"(hr[RR0+4]), "v"(hr[RR0+5]), "v"(hr[RR0+6]), "v"(hr[RR0+7]),     \
          "v"(wv[(Q)*16+(RR0)+0]), "v"(wv[(Q)*16+(RR0)+1]),                   \
          "v"(wv[(Q)*16+(RR0)+2]), "v"(wv[(Q)*16+(RR0)+3]),                   \
          "v"(wv[(Q)*16+(RR0)+4]), "v"(wv[(Q)*16+(RR0)+5]),                   \
          "v"(wv[(Q)*16+(RR0)+6]), "v"(wv[(Q)*16+(RR0)+7]))

__global__ __launch_bounds__(1024, 4)
void lstm_persist(
    const float* Whh_f, const float* Whh_b,            // NOT restrict (anti-remat)
    const float* __restrict__ h0, const float* __restrict__ c0,
    const float* __restrict__ gin,
    float* Hh)                                          // [T][512], 0x7F-filled
{
    const int blk = blockIdx.x;
    const int m8  = blk & 7;
    if (m8 != 0 && m8 != 4) return;     // XCD placement spacers
    const int dir = (m8 == 4);
    const int b   = blk >> 3;           // unit-slice 0..3
    const int tid = threadIdx.x;
    const int u     = tid & 63;
    const int wvid  = tid >> 6;         // 0..15
    const int gate  = wvid >> 2;        // wave-uniform
    const int q     = wvid & 3;         // wave-uniform quarter (col window)
    const int unit0 = b*64;
    const int row   = gate*64 + u;            // block-local row 0..255
    const int grow  = gate*HD + unit0 + u;    // gate row 0..1023

    // --- load + pin 64 weights (quarter gate row) in VGPRs ---
    const float* wrow = (dir ? Whh_b : Whh_f) + (long)grow*HD + q*64;
    float wv[64];
    #pragma unroll
    for (int k = 0; k < 16; ++k) {
        const float4 v = ((const float4*)wrow)[k];
        wv[4*k+0]=v.x; wv[4*k+1]=v.y; wv[4*k+2]=v.z; wv[4*k+3]=v.w;
        asm volatile("" : "+v"(wv[4*k+0]), "+v"(wv[4*k+1]),
                          "+v"(wv[4*k+2]), "+v"(wv[4*k+3]));
    }

    // 80 KB hS (only [0..255] used): LDS-forces 1 block/CU so the allocator
    // cannot gain occupancy by spilling -> full 128-VGPR/wave budget usable.
    __shared__ __align__(16) float hS[20480];
    __shared__ float ps[3][256];    // quarter 1..3 partial sums [q-1][row]
    __shared__ float gvS[256];      // activated gates [gate*64+u]

    float cst = 0.f;
    if (tid < 64) cst = c0[dir*HD + unit0 + tid];       // owners: wave 0
    if (tid < HD) hS[tid] = h0[dir*HD + tid];

    const float* ginD = gin + dir*G4;
    unsigned int* HhU = (unsigned int*)Hh;
    float gx = (q == 0) ? ginD[(long)(dir ? T_LEN-1 : 0)*N2 + grow] : 0.f;

    #pragma unroll 1
    for (int s = 0; s < T_LEN; ++s) {
        const int t = dir ? (T_LEN-1-s) : s;
        float gxn = 0.f;
        if (q == 0 && s+1 < T_LEN)             // prefetch next step's gin
            gxn = ginD[(long)(dir ? t-1 : t+1)*N2 + grow];

        __syncthreads();                       // (A) hS(s) complete
        // lane-spread h window: lane l holds h[q*64 + (l&3)*16 + 0..15]
        const float* hw = hS + q*64 + (tid & 3)*16;
        float hr[16];
        *(float4*)&hr[0]  = *(const float4*)&hw[0];
        *(float4*)&hr[4]  = *(const float4*)&hw[4];
        *(float4*)&hr[8]  = *(const float4*)&hw[8];
        *(float4*)&hr[12] = *(const float4*)&hw[12];

        float ac0=0.f, ac1=0.f, ac2=0.f, ac3=0.f;
        FMA8(0, 0); FMA8(0, 8);
        FMA8(1, 0); FMA8(1, 8);
        FMA8(2, 0); FMA8(2, 8);
        FMA8(3, 0); FMA8(3, 8);
        const float a = (ac0+ac1)+(ac2+ac3);

        if (q != 0) ps[q-1][row] = a;
        __syncthreads();                       // (B) partials ready

        if (q == 0) {                          // waves 0,4,8,12: finalize + activate
            const float raw = a + ps[0][row] + ps[1][row] + ps[2][row] + gx;
            gvS[row] = (gate == 2) ? tanhf(raw) : 1.f/(1.f + expf(-raw));
        }
        __syncthreads();                       // (C) gvS ready

        if (tid < 64) {                        // wave 0 = owners: c/h update + publish
            const float i_ = gvS[tid],       f_ = gvS[64+tid];
            const float g_ = gvS[128+tid],   o_ = gvS[192+tid];
            cst = fmaf(f_, cst, i_*g_);
            const float hv = o_ * tanhf(cst);
            hS[unit0 + tid] = hv;              // own slice: LDS only
            __hip_atomic_store(&HhU[(long)t*512 + dir*HD + unit0 + tid],
                               __float_as_uint(hv),
                               __ATOMIC_RELAXED, __HIP_MEMORY_SCOPE_AGENT);
        } else if (tid < 256 && s+1 < T_LEN) { // waves 1-3: poll one foreign word each
            const int fidx = tid - 64;                      // 0..191
            const int gu   = (fidx < unit0) ? fidx : fidx + 64;
            const long idx = (long)t*512 + dir*HD + gu;
            unsigned int v;
            do {
                v = __hip_atomic_load(&HhU[idx], __ATOMIC_RELAXED,
                                      __HIP_MEMORY_SCOPE_AGENT);
            } while (v == SENT);
            hS[gu] = __uint_as_float(v);
        }
        gx = gxn;
    }
}

// ---------------------------------------------------------------------------
// Kernel 3: feats[t][tag] = [hf|hb][t] . W_tag[tag] + b_tag
// ---------------------------------------------------------------------------
__global__ __launch_bounds__(192) void feats_kernel(
    const float* __restrict__ Hhist, const float* __restrict__ Wtag,
    const float* __restrict__ btag, float* __restrict__ feats)
{
    __shared__ __align__(16) float Ws[TAGS][512];
    const int tid = threadIdx.x;
    for (int i = tid; i < TAGS*512; i += 192) Ws[0][i] = Wtag[i];
    __syncthreads();
    const int tl = tid / TAGS;            // 0..15
    const int tg = tid % TAGS;
    const int t  = blockIdx.x * 16 + tl;
    const float4* hrow = (const float4*)(Hhist + (long)t*512);
    const float4* wrow = (const float4*)(&Ws[tg][0]);
    float a0=0.f,a1=0.f,a2=0.f,a3=0.f;
    #pragma unroll 8
    for (int k = 0; k < 128; ++k) {
        const float4 h = hrow[k];
        const float4 ww = wrow[k];
        a0=fmaf(h.x,ww.x,a0); a1=fmaf(h.y,ww.y,a1);
        a2=fmaf(h.z,ww.z,a2); a3=fmaf(h.w,ww.w,a3);
    }
    feats[t*TAGS + tg] = ((a0+a1)+(a2+a3)) + btag[tg];
}

// ---------------------------------------------------------------------------
// Kernel 4: Viterbi forward scan (12 lanes) + serial backtrack.
// ---------------------------------------------------------------------------
__global__ __launch_bounds__(256) void viterbi_kernel(
    const float* __restrict__ feats, const float* __restrict__ trans,
    float* __restrict__ out)
{
    __shared__ float fS[256*TAGS];                 // 12 KB feats chunk
    __shared__ unsigned char bps[T_LEN*TAGS];      // 48 KB backpointers
    __shared__ float fvS[TAGS];
    const int tid = threadIdx.x;

    float tr[TAGS];
    float fv = NEGV;
    if (tid < TAGS) {
        #pragma unroll
        for (int f = 0; f < TAGS; ++f) tr[f] = trans[tid*TAGS + f];
        fv = (tid == 10) ? 0.f : NEGV;             // START = 10
    }

    for (int c = 0; c < T_LEN/256; ++c) {
        __syncthreads();
        for (int i = tid; i < 256*TAGS; i += 256) fS[i] = feats[c*256*TAGS + i];
        __syncthreads();
        if (tid < TAGS) {
            for (int s = 0; s < 256; ++s) {
                float best = -3.4e38f; int bp = 0;
                #pragma unroll
                for (int f = 0; f < TAGS; ++f) {
                    const float v = __shfl(fv, f, 64) + tr[f];
                    if (v > best) { best = v; bp = f; }   // strict > = np argmax semantics
                }
                bps[(c*256+s)*TAGS + tid] = (unsigned char)bp;
                fv = best + fS[s*TAGS + tid];
            }
        }
    }
    __syncthreads();
    if (tid < TAGS) fvS[tid] = fv + trans[11*TAGS + tid];  // STOP = 11
    __syncthreads();
    if (tid == 0) {
        float bestv = fvS[0]; int best = 0;
        #pragma unroll
        for (int g = 1; g < TAGS; ++g) if (fvS[g] > bestv) { bestv = fvS[g]; best = g; }
        out[0] = bestv;
        int cur = best;
        for (int t = T_LEN-1; t >= 0; --t) {
            out[1+t] = (float)cur;
            cur = bps[t*TAGS + cur];
        }
    }
}

// ---------------------------------------------------------------------------
// Host launch.  ws layout (floats):
//   gin   [4096*2048] = 33.5 MB
//   Hh    [4096*512]  =  8.4 MB  (sentinel-initialized each launch)
//   feats [4096*12]   =  0.2 MB
// ---------------------------------------------------------------------------
extern "C" void kernel_launch(void* const* d_in, const int* in_sizes, int n_in,
                              void* d_out, int out_size, void* d_ws, size_t ws_size,
                              hipStream_t stream)
{
    (void)in_sizes; (void)n_in; (void)out_size; (void)ws_size;
    const int*   sentence = (const int*)  d_in[0];
    const float* h0       = (const float*)d_in[1];
    const float* c0       = (const float*)d_in[2];
    const float* embed    = (const float*)d_in[3];
    const float* Wihf     = (const float*)d_in[4];
    const float* Whhf     = (const float*)d_in[5];
    const float* bihf     = (const float*)d_in[6];
    const float* bhhf     = (const float*)d_in[7];
    const float* Wihb     = (const float*)d_in[8];
    const float* Whhb     = (const float*)d_in[9];
    const float* bihb     = (const float*)d_in[10];
    const float* bhhb     = (const float*)d_in[11];
    const float* Wtag     = (const float*)d_in[12];
    const float* btag     = (const float*)d_in[13];
    const float* trans    = (const float*)d_in[14];
    float* out = (float*)d_out;

    float* gin   = (float*)d_ws;
    float* Hh    = gin + (long)T_LEN*N2;
    float* feats = Hh  + (long)T_LEN*512;

    // sentinel-fill Hh: data-is-the-flag protocol
    hipMemsetAsync(Hh, 0x7F, (size_t)T_LEN*512*sizeof(float), stream);

    dim3 ggrid(32, 64);
    gin_gemm<<<ggrid, 256, 0, stream>>>(sentence, embed, Wihf, Wihb,
                                        bihf, bhhf, bihb, bhhb, gin);
    lstm_persist<<<29, 1024, 0, stream>>>(Whhf, Whhb, h0, c0, gin, Hh);
    feats_kernel<<<T_LEN/16, 192, 0, stream>>>(Hh, Wtag, btag, feats);
    viterbi_kernel<<<1, 256, 0, stream>>>(feats, trans, out);
}

// Round 10
// 7203.606 us; speedup vs baseline: 1.0165x; 1.0165x over previous
//
#include <hip/hip_runtime.h>

#define T_LEN 4096
#define EMB   300
#define HD    256
#define G4    1024      // 4*HD (gate rows per direction)
#define N2    2048      // both directions
#define TAGS  12
#define NEGV  -10000.0f
#define SENT  0x7F7F7F7Fu   // memset byte 0x7F -> 3.396e38f; |h|<1 so never produced

// ---------------------------------------------------------------------------
// Kernel 1: g_in[t][dir*1024 + r] = embed[sent[t]] . W_ih_dir[r] + b_ih + b_hh
// 64x64 tiles, 256 thr, 4x4 acc, transposed LDS staging.
// ---------------------------------------------------------------------------
__global__ __launch_bounds__(256) void gin_gemm(
    const int* __restrict__ sent, const float* __restrict__ embed,
    const float* __restrict__ Wf, const float* __restrict__ Wb,
    const float* __restrict__ bihf, const float* __restrict__ bhhf,
    const float* __restrict__ bihb, const float* __restrict__ bhhb,
    float* __restrict__ gin)
{
    __shared__ float AsT[32][68];
    __shared__ float BsT[32][68];
    __shared__ int   sIdx[64];
    const int tid = threadIdx.x;
    const int bn = blockIdx.x;   // 0..31  (N tiles over 2048)
    const int bm = blockIdx.y;   // 0..63  (M tiles over 4096)
    if (tid < 64) sIdx[tid] = sent[bm*64 + tid];
    __syncthreads();

    float acc[4][4] = {};
    const int lr = tid >> 3;          // 0..31
    const int lk = (tid & 7) << 2;    // 0,4,..,28
    const int m0 = (tid >> 4) << 2;
    const int n0 = (tid & 15) << 2;

    for (int kc = 0; kc < 10; ++kc) {           // K chunks of 32 (covers 320, guard 300)
        const int k0 = kc*32 + lk;
        #pragma unroll
        for (int h = 0; h < 2; ++h) {
            const int row = lr + h*32;
            float4 va = make_float4(0.f,0.f,0.f,0.f);
            if (k0 + 3 < EMB)   // EMB % 4 == 0: vectors are all-or-nothing
                va = *(const float4*)(embed + (long)sIdx[row]*EMB + k0);
            AsT[lk+0][row]=va.x; AsT[lk+1][row]=va.y;
            AsT[lk+2][row]=va.z; AsT[lk+3][row]=va.w;

            const int rn = bn*64 + row;          // tiles never straddle the 1024 split
            const float* bsrc = (rn < G4) ? (Wf + (long)rn*EMB) : (Wb + (long)(rn-G4)*EMB);
            float4 vb = make_float4(0.f,0.f,0.f,0.f);
            if (k0 + 3 < EMB)
                vb = *(const float4*)(bsrc + k0);
            BsT[lk+0][row]=vb.x; BsT[lk+1][row]=vb.y;
            BsT[lk+2][row]=vb.z; BsT[lk+3][row]=vb.w;
        }
        __syncthreads();
        #pragma unroll
        for (int kk = 0; kk < 32; ++kk) {
            const float4 a4 = *(const float4*)&AsT[kk][m0];
            const float4 b4 = *(const float4*)&BsT[kk][n0];
            const float a[4] = {a4.x, a4.y, a4.z, a4.w};
            const float b[4] = {b4.x, b4.y, b4.z, b4.w};
            #pragma unroll
            for (int i = 0; i < 4; ++i)
                #pragma unroll
                for (int jj = 0; jj < 4; ++jj)
                    acc[i][jj] = fmaf(a[i], b[jj], acc[i][jj]);
        }
        __syncthreads();
    }

    #pragma unroll
    for (int i = 0; i < 4; ++i) {
        const int t = bm*64 + m0 + i;
        #pragma unroll
        for (int jj = 0; jj < 4; ++jj) {
            const int r = bn*64 + n0 + jj;
            const float bias = (r < G4) ? (bihf[r] + bhhf[r])
                                        : (bihb[r-G4] + bhhb[r-G4]);
            gin[(long)t*N2 + r] = acc[i][jj] + bias;
        }
    }
}

// ---------------------------------------------------------------------------
// Kernel 2: persistent BiLSTM, 4 blocks x 1024 thr per direction.
// r8 partition (quarter gate-rows, 64 weights/thread, one-hop sentinel
// exchange), weight residency redesigned:
//  * weights = 16 NAMED float4 SSA locals (no array, no address-taken,
//    NO asm) -> SROA-proof; scratch impossible unless regalloc spills.
//  * anti-remat by ALIASING: Whh_* and Hh are non-restrict float*, and the
//    loop publishes h through Hh as float -> reloading weights after the
//    store is illegal, so values must be carried in registers.
//  * amdgpu_waves_per_eu(4,4) + 80 KB LDS pin 1 block/CU, 4 waves/EU ->
//    VGPR cap 128, no occupancy incentive to spill (~105 needed).
// ---------------------------------------------------------------------------
#define MV(K) { const float4 hv = h4[K];                    \
    a0 = fmaf(wA##K.x, hv.x, a0);                           \
    a1 = fmaf(wA##K.y, hv.y, a1);                           \
    a2 = fmaf(wA##K.z, hv.z, a2);                           \
    a3 = fmaf(wA##K.w, hv.w, a3); }

__global__ __launch_bounds__(1024) __attribute__((amdgpu_waves_per_eu(4, 4)))
void lstm_persist(
    const float* Whh_f, const float* Whh_b,            // NOT restrict (on purpose)
    const float* __restrict__ h0, const float* __restrict__ c0,
    const float* __restrict__ gin,
    float* Hh)                                          // NOT restrict; [T][512], 0x7F-filled
{
    const int blk = blockIdx.x;
    const int m8  = blk & 7;
    if (m8 != 0 && m8 != 4) return;     // XCD placement spacers
    const int dir = (m8 == 4);
    const int b   = blk >> 3;           // unit-slice 0..3
    const int tid = threadIdx.x;
    const int u     = tid & 63;
    const int wvid  = tid >> 6;         // 0..15
    const int gate  = wvid >> 2;        // wave-uniform
    const int q     = wvid & 3;         // wave-uniform quarter (col window)
    const int unit0 = b*64;
    const int row   = gate*64 + u;            // block-local row 0..255
    const int grow  = gate*HD + unit0 + u;    // gate row 0..1023

    // --- 64 weights as pure SSA: 16 named float4, loaded once ---
    const float4* W4 = (const float4*)((dir ? Whh_b : Whh_f)
                                       + (long)grow*HD + q*64);
    const float4 wA0  = W4[0],  wA1  = W4[1],  wA2  = W4[2],  wA3  = W4[3];
    const float4 wA4  = W4[4],  wA5  = W4[5],  wA6  = W4[6],  wA7  = W4[7];
    const float4 wA8  = W4[8],  wA9  = W4[9],  wA10 = W4[10], wA11 = W4[11];
    const float4 wA12 = W4[12], wA13 = W4[13], wA14 = W4[14], wA15 = W4[15];

    // 80 KB hS (only [0..255] used): LDS-forces 1 block/CU.
    __shared__ __align__(16) float hS[20480];
    __shared__ float ps[3][256];    // quarter 1..3 partial sums [q-1][row]
    __shared__ float gvS[256];      // activated gates [gate*64+u]

    float cst = 0.f;
    if (tid < 64) cst = c0[dir*HD + unit0 + tid];       // owners: wave 0
    if (tid < HD) hS[tid] = h0[dir*HD + tid];

    const float* ginD = gin + dir*G4;
    float gx = (q == 0) ? ginD[(long)(dir ? T_LEN-1 : 0)*N2 + grow] : 0.f;

    #pragma unroll 1
    for (int s = 0; s < T_LEN; ++s) {
        const int t = dir ? (T_LEN-1-s) : s;
        float gxn = 0.f;
        if (q == 0 && s+1 < T_LEN)             // prefetch next step's gin
            gxn = ginD[(long)(dir ? t-1 : t+1)*N2 + grow];

        __syncthreads();                       // (A) hS(s) complete
        const float4* h4 = (const float4*)(hS + q*64);   // uniform-addr broadcast
        float a0=0.f, a1=0.f, a2=0.f, a3=0.f;
        MV(0)  MV(1)  MV(2)  MV(3)
        MV(4)  MV(5)  MV(6)  MV(7)
        MV(8)  MV(9)  MV(10) MV(11)
        MV(12) MV(13) MV(14) MV(15)
        const float a = (a0+a1)+(a2+a3);

        if (q != 0) ps[q-1][row] = a;
        __syncthreads();                       // (B) partials ready

        if (q == 0) {                          // waves 0,4,8,12: finalize + activate
            const float raw = a + ps[0][row] + ps[1][row] + ps[2][row] + gx;
            gvS[row] = (gate == 2) ? tanhf(raw) : 1.f/(1.f + expf(-raw));
        }
        __syncthreads();                       // (C) gvS ready

        if (tid < 64) {                        // wave 0 = owners: c/h update + publish
            const float i_ = gvS[tid],       f_ = gvS[64+tid];
            const float g_ = gvS[128+tid],   o_ = gvS[192+tid];
            cst = fmaf(f_, cst, i_*g_);
            const float hv = o_ * tanhf(cst);
            hS[unit0 + tid] = hv;              // own slice: LDS only
            // publish as FLOAT (same type as Whh -> may-alias -> weights
            // must stay live in registers across the loop)
            __hip_atomic_store(&Hh[(long)t*512 + dir*HD + unit0 + tid], hv,
                               __ATOMIC_RELAXED, __HIP_MEMORY_SCOPE_AGENT);
        } else if (tid < 256 && s+1 < T_LEN) { // waves 1-3: poll one foreign word each
            const int fidx = tid - 64;                      // 0..191
            const int gu   = (fidx < unit0) ? fidx : fidx + 64;
            const long idx = (long)t*512 + dir*HD + gu;
            float v;
            do {
                v = __hip_atomic_load(&Hh[idx], __ATOMIC_RELAXED,
                                      __HIP_MEMORY_SCOPE_AGENT);
            } while (__float_as_uint(v) == SENT);
            hS[gu] = v;
        }
        gx = gxn;
    }
}

// ---------------------------------------------------------------------------
// Kernel 3: feats[t][tag] = [hf|hb][t] . W_tag[tag] + b_tag
// ---------------------------------------------------------------------------
__global__ __launch_bounds__(192) void feats_kernel(
    const float* __restrict__ Hhist, const float* __restrict__ Wtag,
    const float* __restrict__ btag, float* __restrict__ feats)
{
    __shared__ __align__(16) float Ws[TAGS][512];
    const int tid = threadIdx.x;
    for (int i = tid; i < TAGS*512; i += 192) Ws[0][i] = Wtag[i];
    __syncthreads();
    const int tl = tid / TAGS;            // 0..15
    const int tg = tid % TAGS;
    const int t  = blockIdx.x * 16 + tl;
    const float4* hrow = (const float4*)(Hhist + (long)t*512);
    const float4* wrow = (const float4*)(&Ws[tg][0]);
    float a0=0.f,a1=0.f,a2=0.f,a3=0.f;
    #pragma unroll 8
    for (int k = 0; k < 128; ++k) {
        const float4 h = hrow[k];
        const float4 ww = wrow[k];
        a0=fmaf(h.x,ww.x,a0); a1=fmaf(h.y,ww.y,a1);
        a2=fmaf(h.z,ww.z,a2); a3=fmaf(h.w,ww.w,a3);
    }
    feats[t*TAGS + tg] = ((a0+a1)+(a2+a3)) + btag[tg];
}

// ---------------------------------------------------------------------------
// Kernel 4: Viterbi forward scan (12 lanes) + serial backtrack.
// ---------------------------------------------------------------------------
__global__ __launch_bounds__(256) void viterbi_kernel(
    const float* __restrict__ feats, const float* __restrict__ trans,
    float* __restrict__ out)
{
    __shared__ float fS[256*TAGS];                 // 12 KB feats chunk
    __shared__ unsigned char bps[T_LEN*TAGS];      // 48 KB backpointers
    __shared__ float fvS[TAGS];
    const int tid = threadIdx.x;

    float tr[TAGS];
    float fv = NEGV;
    if (tid < TAGS) {
        #pragma unroll
        for (int f = 0; f < TAGS; ++f) tr[f] = trans[tid*TAGS + f];
        fv = (tid == 10) ? 0.f : NEGV;             // START = 10
    }

    for (int c = 0; c < T_LEN/256; ++c) {
        __syncthreads();
        for (int i = tid; i < 256*TAGS; i += 256) fS[i] = feats[c*256*TAGS + i];
        __syncthreads();
        if (tid < TAGS) {
            for (int s = 0; s < 256; ++s) {
                float best = -3.4e38f; int bp = 0;
                #pragma unroll
                for (int f = 0; f < TAGS; ++f) {
                    const float v = __shfl(fv, f, 64) + tr[f];
                    if (v > best) { best = v; bp = f; }   // strict > = np argmax semantics
                }
                bps[(c*256+s)*TAGS + tid] = (unsigned char)bp;
                fv = best + fS[s*TAGS + tid];
            }
        }
    }
    __syncthreads();
    if (tid < TAGS) fvS[tid] = fv + trans[11*TAGS + tid];  // STOP = 11
    __syncthreads();
    if (tid == 0) {
        float bestv = fvS[0]; int best = 0;
        #pragma unroll
        for (int g = 1; g < TAGS; ++g) if (fvS[g] > bestv) { bestv = fvS[g]; best = g; }
        out[0] = bestv;
        int cur = best;
        for (int t = T_LEN-1; t >= 0; --t) {
            out[1+t] = (float)cur;
            cur = bps[t*TAGS + cur];
        }
    }
}

// ---------------------------------------------------------------------------
// Host launch.  ws layout (floats):
//   gin   [4096*2048] = 33.5 MB
//   Hh    [4096*512]  =  8.4 MB  (sentinel-initialized each launch)
//   feats [4096*12]   =  0.2 MB
// ---------------------------------------------------------------------------
extern "C" void kernel_launch(void* const* d_in, const int* in_sizes, int n_in,
                              void* d_out, int out_size, void* d_ws, size_t ws_size,
                              hipStream_t stream)
{
    (void)in_sizes; (void)n_in; (void)out_size; (void)ws_size;
    const int*   sentence = (const int*)  d_in[0];
    const float* h0       = (const float*)d_in[1];
    const float* c0       = (const float*)d_in[2];
    const float* embed    = (const float*)d_in[3];
    const float* Wihf     = (const float*)d_in[4];
    const float* Whhf     = (const float*)d_in[5];
    const float* bihf     = (const float*)d_in[6];
    const float* bhhf     = (const float*)d_in[7];
    const float* Wihb     = (const float*)d_in[8];
    const float* Whhb     = (const float*)d_in[9];
    const float* bihb     = (const float*)d_in[10];
    const float* bhhb     = (const float*)d_in[11];
    const float* Wtag     = (const float*)d_in[12];
    const float* btag     = (const float*)d_in[13];
    const float* trans    = (const float*)d_in[14];
    float* out = (float*)d_out;

    float* gin   = (float*)d_ws;
    float* Hh    = gin + (long)T_LEN*N2;
    float* feats = Hh  + (long)T_LEN*512;

    // sentinel-fill Hh: data-is-the-flag protocol
    hipMemsetAsync(Hh, 0x7F, (size_t)T_LEN*512*sizeof(float), stream);

    dim3 ggrid(32, 64);
    gin_gemm<<<ggrid, 256, 0, stream>>>(sentence, embed, Wihf, Wihb,
                                        bihf, bhhf, bihb, bhhb, gin);
    lstm_persist<<<29, 1024, 0, stream>>>(Whhf, Whhb, h0, c0, gin, Hh);
    feats_kernel<<<T_LEN/16, 192, 0, stream>>>(Hh, Wtag, btag, feats);
    viterbi_kernel<<<1, 256, 0, stream>>>(feats, trans, out);
}